// Round 9
// baseline (151.677 us; speedup 1.0000x reference)
//
#include <hip/hip_runtime.h>
#include <math.h>

#define B_    16
#define T_    512
#define D_    2048
#define DS_   4096
#define TG_   128            // t-groups of 4 rows
#define RS_   2052           // padded LDS row stride (floats) -> rows 4 banks apart
#define EPS_  1e-8f
#define CLOG  34.5f          // e^-34.5 ~ 1e-15 drop threshold

// ws (floats unless noted): num[TG_*B_*DS_] | inv_den[DS_] | g_s[DS_] | nr_s[DS_]
//                           | pair_s[DS_] (int) | nout_s[DS_] (int) | hcap_s[DS_] (int)

__device__ __forceinline__ float softplus_f(float x) {
    return (x > 20.f) ? x : log1pf(expf(x));
}

__device__ __forceinline__ void glds16(const float* g, float* l) {
    __builtin_amdgcn_global_load_lds((const __attribute__((address_space(1))) void*)g,
                                     (__attribute__((address_space(3))) void*)l,
                                     16, 0, 0);
}

__global__ __launch_bounds__(256) void pre_kernel(const float* __restrict__ decay_rates,
                                                  float* __restrict__ inv_den) {
    int n = blockIdx.x * 256 + threadIdx.x;          // 4096
    float r = softplus_f(decay_rates[n]);
    float S = expm1f(-r * (float)T_) / expm1f(-r);   // exact geometric sum
    inv_den[n] = 1.0f / sqrtf(S + EPS_);
}

// Counting sort of n by horizon bucket, DESCENDING horizon (wave-uniform liveness).
__global__ __launch_bounds__(1024) void sort_kernel(const float* __restrict__ decay_rates,
                                                    const int* __restrict__ idx_i,
                                                    const int* __restrict__ idx_j,
                                                    float* __restrict__ g_s,
                                                    float* __restrict__ nr_s,
                                                    int* __restrict__ pair_s,
                                                    int* __restrict__ nout_s,
                                                    int* __restrict__ hcap_s) {
    __shared__ int hist[64];
    const int tid = threadIdx.x;
    if (tid < 64) hist[tid] = 0;
    __syncthreads();
    #pragma unroll
    for (int k = 0; k < 4; ++k) {
        int n = tid + k * 1024;
        float r = softplus_f(decay_rates[n]);
        float hf = CLOG / r;
        int h = (hf >= 511.f) ? 511 : (int)hf;       // inf-safe cap
        atomicAdd(&hist[h >> 3], 1);
    }
    __syncthreads();
    if (tid == 0) {                                   // exclusive scan, descending bucket
        int run = 0;
        for (int q = 63; q >= 0; --q) { int c = hist[q]; hist[q] = run; run += c; }
    }
    __syncthreads();
    #pragma unroll
    for (int k = 0; k < 4; ++k) {
        int n = tid + k * 1024;
        float r = softplus_f(decay_rates[n]);
        float hf = CLOG / r;
        int h = (hf >= 511.f) ? 511 : (int)hf;
        int q = h >> 3;
        int pos = atomicAdd(&hist[q], 1);
        g_s[pos]    = expf(r);
        nr_s[pos]   = -r;
        pair_s[pos] = idx_i[n] | (idx_j[n] << 16);
        nout_s[pos] = n;
        hcap_s[pos] = (q << 3) | 7;                   // conservative bound, monotone desc
    }
}

__global__ __launch_bounds__(256) void main_kernel(const float* __restrict__ z,
                                                   const float* __restrict__ g_s,
                                                   const float* __restrict__ nr_s,
                                                   const int* __restrict__ pair_s,
                                                   const int* __restrict__ hcap_s,
                                                   float* __restrict__ num) {
    __shared__ float rows[4 * RS_];                   // 32.8 KB -> 4 blocks/CU
    const int tg   = blockIdx.x;                      // 0..127
    const int b    = blockIdx.y;                      // 0..15
    const int tid  = threadIdx.x;
    const int wave = tid >> 6, lane = tid & 63;
    const int tb   = tg * 4;
    const int kminB = 508 - tb;                       // smallest exponent in block
    const int kb0   = 511 - tb;                       // exponent at local row 0

    // Async stage: wave w owns global row w; 8 x 1KB fire-and-forget segments.
    const float* src = z + ((size_t)b * T_ + tb + wave) * D_ + lane * 4;
    float* dst = rows + wave * RS_;
    #pragma unroll
    for (int s = 0; s < 8; ++s)
        glds16(src + s * 256, dst + s * 256);

    // Overlap with staging: liveness + params (L2-cached sorted arrays).
    int hcv[16];
    #pragma unroll
    for (int s = 0; s < 16; ++s) hcv[s] = hcap_s[tid + s * 256];
    int hb[16], pair[16]; float g[16], w0[16];
    #pragma unroll
    for (int s = 0; s < 16; ++s) {
        hb[s] = __builtin_amdgcn_readfirstlane(hcv[s]);   // lane0 = wave max (sorted)
        if (hb[s] >= kminB) {
            int m = tid + s * 256;
            pair[s] = pair_s[m];
            g[s]    = g_s[m];
            w0[s]   = __expf(nr_s[m] * (float)kb0);
        }
    }

    asm volatile("s_waitcnt vmcnt(0)" ::: "memory");
    __syncthreads();

    #pragma unroll
    for (int s = 0; s < 16; ++s) {
        if (hb[s] >= kminB) {                         // wave-uniform skip
            int ci = pair[s] & 0xFFFF, cj = pair[s] >> 16;
            float vi0 = rows[ci],           vj0 = rows[cj];
            float vi1 = rows[RS_ + ci],     vj1 = rows[RS_ + cj];
            float vi2 = rows[2 * RS_ + ci], vj2 = rows[2 * RS_ + cj];
            float vi3 = rows[3 * RS_ + ci], vj3 = rows[3 * RS_ + cj];
            float gs = g[s];
            float h3 = vi3 * vj3;
            float h2 = fmaf(h3, gs, vi2 * vj2);
            float h1 = fmaf(h2, gs, vi1 * vj1);
            float h0 = fmaf(h1, gs, vi0 * vj0);
            num[((size_t)tg * B_ + b) * DS_ + tid + s * 256] = w0[s] * h0;  // coalesced
        }
    }
}

__global__ __launch_bounds__(256) void fin_kernel(const float* __restrict__ num,
                                                  const float* __restrict__ inv_den,
                                                  const int* __restrict__ nout_s,
                                                  const int* __restrict__ hcap_s,
                                                  float* __restrict__ out) {
    int gt = blockIdx.x * 256 + threadIdx.x;          // 0..65535
    int m  = gt & (DS_ - 1);
    int b  = gt >> 12;
    int hc = hcap_s[(m >> 6) << 6];                   // same wave-leader rule as main
    int tgmin = (511 - hc) >> 2; if (tgmin < 0) tgmin = 0;
    float sum = 0.f;
    for (int tg = tgmin; tg < TG_; ++tg)              // uniform per 64-lane group
        sum += num[((size_t)tg * B_ + b) * DS_ + m];  // coalesced
    int n = nout_s[m];
    out[b * DS_ + n] = sum * inv_den[n];
}

extern "C" void kernel_launch(void* const* d_in, const int* in_sizes, int n_in,
                              void* d_out, int out_size, void* d_ws, size_t ws_size,
                              hipStream_t stream) {
    const float* z  = (const float*)d_in[0];   // (16,512,2048) f32
    const float* dr = (const float*)d_in[1];   // (4096,) f32
    const int*   ii = (const int*)d_in[2];     // (4096,) i32
    const int*   jj = (const int*)d_in[3];     // (4096,) i32
    float* out = (float*)d_out;                // (16,4096) f32

    float* num     = (float*)d_ws;                    // TG_*B_*DS_ = 33.5 MB
    float* inv_den = num + (size_t)TG_ * B_ * DS_;
    float* g_s     = inv_den + DS_;
    float* nr_s    = g_s + DS_;
    int*   pair_s  = (int*)(nr_s + DS_);
    int*   nout_s  = pair_s + DS_;
    int*   hcap_s  = nout_s + DS_;

    hipLaunchKernelGGL(pre_kernel, dim3(DS_ / 256), dim3(256), 0, stream, dr, inv_den);
    hipLaunchKernelGGL(sort_kernel, dim3(1), dim3(1024), 0, stream,
                       dr, ii, jj, g_s, nr_s, pair_s, nout_s, hcap_s);
    hipLaunchKernelGGL(main_kernel, dim3(TG_, B_), dim3(256), 0, stream,
                       z, g_s, nr_s, pair_s, hcap_s, num);
    hipLaunchKernelGGL(fin_kernel, dim3((B_ * DS_) / 256), dim3(256), 0, stream,
                       num, inv_den, nout_s, hcap_s, out);
}

// Round 11
// 146.862 us; speedup vs baseline: 1.0328x; 1.0328x over previous
//
#include <hip/hip_runtime.h>
#include <math.h>

#define B_    16
#define T_    512
#define D_    2048
#define DS_   4096
#define TG_   128            // t-groups of 4 rows
#define RS_   2052           // padded LDS row stride (floats) -> rows 4 banks apart
#define EPS_  1e-8f
#define CLOG  16.0f          // drop weights < e^-16 (~1e-7 rel; threshold margin ~3000x)

// ws (floats unless noted): num[TG_*B_*DS_] | inv_den[DS_] | g_s[DS_] | nr_s[DS_]
//   | pair_s[DS_] i32 | nout_s[DS_] i32 | hcap_s[DS_] i32 | tgmin_g[16] i32 | smax_g[128] i32

__device__ __forceinline__ float softplus_f(float x) {
    return (x > 20.f) ? x : log1pf(expf(x));
}

__device__ __forceinline__ void glds16(const float* g, float* l) {
    __builtin_amdgcn_global_load_lds((const __attribute__((address_space(1))) void*)g,
                                     (__attribute__((address_space(3))) void*)l,
                                     16, 0, 0);
}

__global__ __launch_bounds__(256) void pre_kernel(const float* __restrict__ decay_rates,
                                                  float* __restrict__ inv_den) {
    int n = blockIdx.x * 256 + threadIdx.x;          // 4096
    float r = softplus_f(decay_rates[n]);
    float S = expm1f(-r * (float)T_) / expm1f(-r);   // exact geometric sum
    inv_den[n] = 1.0f / sqrtf(S + EPS_);
}

// Counting sort by horizon (descending) + per-slot tgmin + per-block smax.
__global__ __launch_bounds__(1024) void sort_kernel(const float* __restrict__ decay_rates,
                                                    const int* __restrict__ idx_i,
                                                    const int* __restrict__ idx_j,
                                                    float* __restrict__ g_s,
                                                    float* __restrict__ nr_s,
                                                    int* __restrict__ pair_s,
                                                    int* __restrict__ nout_s,
                                                    int* __restrict__ hcap_s,
                                                    int* __restrict__ tgmin_g,
                                                    int* __restrict__ smax_g) {
    __shared__ int hist[64];
    __shared__ int tgl[16];
    const int tid = threadIdx.x;
    if (tid < 64) hist[tid] = 0;
    __syncthreads();
    #pragma unroll
    for (int k = 0; k < 4; ++k) {
        int n = tid + k * 1024;
        float r = softplus_f(decay_rates[n]);
        float hf = CLOG / r;
        int h = (hf >= 511.f) ? 511 : (int)hf;       // inf-safe cap
        atomicAdd(&hist[h >> 3], 1);
    }
    __syncthreads();
    if (tid == 0) {                                   // exclusive scan, descending bucket
        int run = 0;
        for (int q = 63; q >= 0; --q) { int c = hist[q]; hist[q] = run; run += c; }
    }
    __syncthreads();
    #pragma unroll
    for (int k = 0; k < 4; ++k) {
        int n = tid + k * 1024;
        float r = softplus_f(decay_rates[n]);
        float hf = CLOG / r;
        int h = (hf >= 511.f) ? 511 : (int)hf;
        int q = h >> 3;
        int pos = atomicAdd(&hist[q], 1);
        g_s[pos]    = expf(r);
        nr_s[pos]   = -r;
        pair_s[pos] = idx_i[n] | (idx_j[n] << 16);
        nout_s[pos] = n;
        hcap_s[pos] = (q << 3) | 7;                   // conservative bound, monotone desc
    }
    __syncthreads();                                  // global writes visible block-wide
    if (tid < 16) {
        int h = hcap_s[tid * 256];                    // slot leader (max h in slot)
        int tm = (511 - h) >> 2;                      // first live block for this slot
        if (tm < 0) tm = 0;
        tgl[tid] = tm;
        tgmin_g[tid] = tm;
    }
    __syncthreads();
    if (tid < TG_) {                                  // smax[tg] = #live slots (prefix)
        int c = 0;
        #pragma unroll
        for (int s = 0; s < 16; ++s) c += (tgl[s] <= tid) ? 1 : 0;
        smax_g[tid] = c;
    }
}

__global__ __launch_bounds__(256) void main_kernel(const float* __restrict__ z,
                                                   const float* __restrict__ g_s,
                                                   const float* __restrict__ nr_s,
                                                   const int* __restrict__ pair_s,
                                                   const int* __restrict__ smax_g,
                                                   float* __restrict__ num) {
    __shared__ float rows[4 * RS_];                   // 32.8 KB -> 4 blocks/CU
    const int tg   = blockIdx.x;                      // 0..127
    const int b    = blockIdx.y;                      // 0..15
    const int tid  = threadIdx.x;
    const int wave = tid >> 6, lane = tid & 63;
    const int tb   = tg * 4;
    const int smax = smax_g[tg];                      // block-uniform scalar
    if (smax == 0) return;                            // uniform: whole block exits

    // Async stage: wave w owns global row w; 8 x 1KB fire-and-forget segments.
    const float* src = z + ((size_t)b * T_ + tb + wave) * D_ + lane * 4;
    float* dst = rows + wave * RS_;
    #pragma unroll
    for (int s = 0; s < 8; ++s)
        glds16(src + s * 256, dst + s * 256);

    const float kb0 = (float)(511 - tb);              // exponent at local row 0
    int pair[16]; float g[16], w0[16];
    #pragma unroll
    for (int s = 0; s < 16; ++s) {
        if (s < smax) {                               // uniform predicate, live prefix only
            int m = tid + s * 256;
            pair[s] = pair_s[m];
            g[s]    = g_s[m];
            w0[s]   = __expf(nr_s[m] * kb0);
        }
    }

    asm volatile("s_waitcnt vmcnt(0)" ::: "memory");
    __syncthreads();

    #pragma unroll
    for (int s = 0; s < 16; ++s) {
        if (s < smax) {
            int ci = pair[s] & 0xFFFF, cj = pair[s] >> 16;
            float vi0 = rows[ci],           vj0 = rows[cj];
            float vi1 = rows[RS_ + ci],     vj1 = rows[RS_ + cj];
            float vi2 = rows[2 * RS_ + ci], vj2 = rows[2 * RS_ + cj];
            float vi3 = rows[3 * RS_ + ci], vj3 = rows[3 * RS_ + cj];
            float gs = g[s];
            float h3 = vi3 * vj3;
            float h2 = fmaf(h3, gs, vi2 * vj2);
            float h1 = fmaf(h2, gs, vi1 * vj1);
            float h0 = fmaf(h1, gs, vi0 * vj0);
            num[((size_t)tg * B_ + b) * DS_ + tid + s * 256] = w0[s] * h0;  // coalesced
        }
    }
}

__global__ __launch_bounds__(256) void fin_kernel(const float* __restrict__ num,
                                                  const float* __restrict__ inv_den,
                                                  const int* __restrict__ nout_s,
                                                  const int* __restrict__ tgmin_g,
                                                  float* __restrict__ out) {
    int gt = blockIdx.x * 256 + threadIdx.x;          // 0..65535
    int m  = gt & (DS_ - 1);
    int b  = gt >> 12;
    int tgmin = tgmin_g[m >> 8];                      // same set as main's stores
    float sum = 0.f;
    for (int tg = tgmin; tg < TG_; ++tg)              // uniform per fin-block (one slot)
        sum += num[((size_t)tg * B_ + b) * DS_ + m];  // coalesced
    int n = nout_s[m];
    out[b * DS_ + n] = sum * inv_den[n];
}

extern "C" void kernel_launch(void* const* d_in, const int* in_sizes, int n_in,
                              void* d_out, int out_size, void* d_ws, size_t ws_size,
                              hipStream_t stream) {
    const float* z  = (const float*)d_in[0];   // (16,512,2048) f32
    const float* dr = (const float*)d_in[1];   // (4096,) f32
    const int*   ii = (const int*)d_in[2];     // (4096,) i32
    const int*   jj = (const int*)d_in[3];     // (4096,) i32
    float* out = (float*)d_out;                // (16,4096) f32

    float* num     = (float*)d_ws;                    // TG_*B_*DS_ = 33.5 MB
    float* inv_den = num + (size_t)TG_ * B_ * DS_;
    float* g_s     = inv_den + DS_;
    float* nr_s    = g_s + DS_;
    int*   pair_s  = (int*)(nr_s + DS_);
    int*   nout_s  = pair_s + DS_;
    int*   hcap_s  = nout_s + DS_;
    int*   tgmin_g = hcap_s + DS_;
    int*   smax_g  = tgmin_g + 16;

    hipLaunchKernelGGL(pre_kernel, dim3(DS_ / 256), dim3(256), 0, stream, dr, inv_den);
    hipLaunchKernelGGL(sort_kernel, dim3(1), dim3(1024), 0, stream,
                       dr, ii, jj, g_s, nr_s, pair_s, nout_s, hcap_s, tgmin_g, smax_g);
    hipLaunchKernelGGL(main_kernel, dim3(TG_, B_), dim3(256), 0, stream,
                       z, g_s, nr_s, pair_s, smax_g, num);
    hipLaunchKernelGGL(fin_kernel, dim3((B_ * DS_) / 256), dim3(256), 0, stream,
                       num, inv_den, nout_s, tgmin_g, out);
}

// Round 12
// 135.173 us; speedup vs baseline: 1.1221x; 1.0865x over previous
//
#include <hip/hip_runtime.h>
#include <math.h>

#define B_    16
#define T_    512
#define D_    2048
#define DS_   4096
#define TG_   128            // t-groups of 4 rows
#define RS_   2052           // padded LDS row stride (floats)
#define EPS_  1e-8f
#define CLOG  16.0f          // drop weights < e^-16 (~1e-7 rel)

// ws (floats unless noted): num[TG_*B_*DS_] | inv_den[DS_] | g_u[DS_] | nr_u[DS_]
//                           | nout_s[DS_] i32 | tgmin_g[16] i32 | smax_g[128] i32

__device__ __forceinline__ float softplus_f(float x) {
    return (x > 20.f) ? x : log1pf(expf(x));
}

__device__ __forceinline__ void glds16(const float* g, float* l) {
    __builtin_amdgcn_global_load_lds((const __attribute__((address_space(1))) void*)g,
                                     (__attribute__((address_space(3))) void*)l,
                                     16, 0, 0);
}

// One prep kernel (single block, 1024 thr): histogram + scan + slot tables +
// per-n params (coalesced, n-order) + ONE scattered array (nout_s).
__global__ __launch_bounds__(1024) void prep_kernel(const float* __restrict__ decay_rates,
                                                    float* __restrict__ inv_den,
                                                    float* __restrict__ g_u,
                                                    float* __restrict__ nr_u,
                                                    int* __restrict__ nout_s,
                                                    int* __restrict__ tgmin_g,
                                                    int* __restrict__ smax_g) {
    __shared__ int hist[64];     // counts -> later scatter cursor
    __shared__ int start_s[64];  // descending-exclusive starts
    __shared__ int tgl[16];
    const int tid = threadIdx.x;
    if (tid < 64) hist[tid] = 0;
    __syncthreads();
    float rv[4]; int qv[4];
    #pragma unroll
    for (int k = 0; k < 4; ++k) {
        int n = tid + k * 1024;
        float r = softplus_f(decay_rates[n]);
        rv[k] = r;
        float hf = CLOG / r;
        int h = (hf >= 511.f) ? 511 : (int)hf;       // inf-safe cap
        qv[k] = h >> 3;
        atomicAdd(&hist[qv[k]], 1);
        float S = expm1f(-r * (float)T_) / expm1f(-r);   // exact geometric sum
        inv_den[n] = 1.0f / sqrtf(S + EPS_);             // coalesced, n-order
        g_u[n]     = expf(r);
        nr_u[n]    = -r;
    }
    __syncthreads();
    if (tid == 0) {                                   // exclusive scan, descending bucket
        int run = 0;
        for (int q = 63; q >= 0; --q) { start_s[q] = run; run += hist[q]; }
    }
    __syncthreads();
    if (tid < 64) hist[tid] = start_s[tid];           // reset cursor for scatter
    if (tid >= 64 && tid < 80) {                      // 16 slot leaders from boundaries
        int s = tid - 64;
        int R = s * 256;                              // leader rank (max-h element of slot)
        int qs = 0;
        for (int q = 63; q >= 0; --q) {
            int nxt = (q == 0) ? DS_ : start_s[q - 1];
            if (start_s[q] <= R && R < nxt) { qs = q; break; }
        }
        int h = (qs << 3) | 7;                        // conservative bound (same as before)
        int tm = (511 - h) >> 2; if (tm < 0) tm = 0;
        tgl[s] = tm;
        tgmin_g[s] = tm;
    }
    __syncthreads();                                  // cursor + tgl ready
    if (tid < TG_) {                                  // smax[tg] = #live slots (prefix)
        int c = 0;
        #pragma unroll
        for (int s = 0; s < 16; ++s) c += (tgl[s] <= tid) ? 1 : 0;
        smax_g[tid] = c;
    }
    #pragma unroll
    for (int k = 0; k < 4; ++k) {                     // the only scattered store
        int n = tid + k * 1024;
        int pos = atomicAdd(&hist[qv[k]], 1);
        nout_s[pos] = n;
    }
}

__global__ __launch_bounds__(256) void main_kernel(const float* __restrict__ z,
                                                   const float* __restrict__ g_u,
                                                   const float* __restrict__ nr_u,
                                                   const int* __restrict__ idx_i,
                                                   const int* __restrict__ idx_j,
                                                   const int* __restrict__ nout_s,
                                                   const int* __restrict__ smax_g,
                                                   float* __restrict__ num) {
    __shared__ float rows[4 * RS_];                   // 32.8 KB -> 4 blocks/CU
    const int tg   = blockIdx.x;                      // 0..127
    const int b    = blockIdx.y;                      // 0..15
    const int tid  = threadIdx.x;
    const int wave = tid >> 6, lane = tid & 63;
    const int tb   = tg * 4;

    // Fire staging FIRST: wave w owns row w; 8 x 1KB fire-and-forget segments.
    const float* src = z + ((size_t)b * T_ + tb + wave) * D_ + lane * 4;
    float* dst = rows + wave * RS_;
    #pragma unroll
    for (int s = 0; s < 8; ++s)
        glds16(src + s * 256, dst + s * 256);

    const int smax = smax_g[tg];                      // block-uniform scalar
    const float kb0 = (float)(511 - tb);              // exponent at local row 0
    int pair[16]; float g[16], w0[16];
    #pragma unroll
    for (int s = 0; s < 16; ++s) {
        if (s < smax) {                               // uniform predicate, live prefix only
            int m = tid + s * 256;
            int n = nout_s[m];                        // coalesced
            pair[s] = idx_i[n] | (idx_j[n] << 16);    // L2-hot gathers (hide under staging)
            g[s]    = g_u[n];
            w0[s]   = __expf(nr_u[n] * kb0);
        }
    }

    asm volatile("s_waitcnt vmcnt(0)" ::: "memory");
    __syncthreads();

    #pragma unroll
    for (int s = 0; s < 16; ++s) {
        if (s < smax) {
            int ci = pair[s] & 0xFFFF, cj = pair[s] >> 16;
            float vi0 = rows[ci],           vj0 = rows[cj];
            float vi1 = rows[RS_ + ci],     vj1 = rows[RS_ + cj];
            float vi2 = rows[2 * RS_ + ci], vj2 = rows[2 * RS_ + cj];
            float vi3 = rows[3 * RS_ + ci], vj3 = rows[3 * RS_ + cj];
            float gs = g[s];
            float h3 = vi3 * vj3;
            float h2 = fmaf(h3, gs, vi2 * vj2);
            float h1 = fmaf(h2, gs, vi1 * vj1);
            float h0 = fmaf(h1, gs, vi0 * vj0);
            num[((size_t)tg * B_ + b) * DS_ + tid + s * 256] = w0[s] * h0;  // coalesced
        }
    }
}

__global__ __launch_bounds__(256) void fin_kernel(const float* __restrict__ num,
                                                  const float* __restrict__ inv_den,
                                                  const int* __restrict__ nout_s,
                                                  const int* __restrict__ tgmin_g,
                                                  float* __restrict__ out) {
    int gt = blockIdx.x * 256 + threadIdx.x;          // 0..65535
    int m  = gt & (DS_ - 1);
    int b  = gt >> 12;
    int tgmin = tgmin_g[m >> 8];                      // same set as main's stores
    float sum = 0.f;
    #pragma unroll 4
    for (int tg = tgmin; tg < TG_; ++tg)              // uniform per fin-block (one slot)
        sum += num[((size_t)tg * B_ + b) * DS_ + m];  // coalesced
    int n = nout_s[m];
    out[b * DS_ + n] = sum * inv_den[n];
}

extern "C" void kernel_launch(void* const* d_in, const int* in_sizes, int n_in,
                              void* d_out, int out_size, void* d_ws, size_t ws_size,
                              hipStream_t stream) {
    const float* z  = (const float*)d_in[0];   // (16,512,2048) f32
    const float* dr = (const float*)d_in[1];   // (4096,) f32
    const int*   ii = (const int*)d_in[2];     // (4096,) i32
    const int*   jj = (const int*)d_in[3];     // (4096,) i32
    float* out = (float*)d_out;                // (16,4096) f32

    float* num     = (float*)d_ws;                    // TG_*B_*DS_ = 33.5 MB
    float* inv_den = num + (size_t)TG_ * B_ * DS_;
    float* g_u     = inv_den + DS_;
    float* nr_u    = g_u + DS_;
    int*   nout_s  = (int*)(nr_u + DS_);
    int*   tgmin_g = nout_s + DS_;
    int*   smax_g  = tgmin_g + 16;

    hipLaunchKernelGGL(prep_kernel, dim3(1), dim3(1024), 0, stream,
                       dr, inv_den, g_u, nr_u, nout_s, tgmin_g, smax_g);
    hipLaunchKernelGGL(main_kernel, dim3(TG_, B_), dim3(256), 0, stream,
                       z, g_u, nr_u, ii, jj, nout_s, smax_g, num);
    hipLaunchKernelGGL(fin_kernel, dim3((B_ * DS_) / 256), dim3(256), 0, stream,
                       num, inv_den, nout_s, tgmin_g, out);
}